// Round 2
// baseline (407.421 us; speedup 1.0000x reference)
//
#include <hip/hip_runtime.h>
#include <cmath>

// Sampler: temperature(0.7) -> top-p(0.9, HF semantics) -> top-k(50)
// -> softmax -> inverse-CDF multinomial with given uniform u.
//
// R2: row-split for occupancy. Kernel A: 16 segments/row, each block computes
// segment max, segment softmax partial (rel. segment max), and extracts a
// superset of the segment's top-50 via an LDS histogram -> per-row candidate
// buffer in workspace. Kernel B: per-row merge (global max, rescaled Z),
// iterative top-min(m,50) selection, exact-path exp, CDF sample.

constexpr int   NSPLIT  = 16;
constexpr int   BLK_A   = 256;
constexpr int   NBINS_A = 1024;
constexpr int   BPL     = NBINS_A / 64;   // bins per lane in wave-0 scan
constexpr int   TOPK    = 50;
constexpr float TEMP    = 0.7f;
constexpr float SPAN    = 8.4f;           // candidate window below segment max
constexpr int   CAPR    = 2048;           // per-row candidate capacity

__global__ void zero_cnt_kernel(unsigned int* cnt, int B) {
  int i = blockIdx.x * blockDim.x + threadIdx.x;
  if (i < B) cnt[i] = 0u;
}

__global__ __launch_bounds__(BLK_A)
void seg_kernel(const float* __restrict__ logits,
                float* __restrict__ segmax, float* __restrict__ segz,
                float* __restrict__ cand_v, int* __restrict__ cand_i,
                unsigned int* __restrict__ cnt,
                int V, int seglen)
{
  const int seg  = blockIdx.x;
  const int row  = blockIdx.y;
  const int tid  = threadIdx.x, lane = tid & 63, wave = tid >> 6;
  const int start = seg * seglen;
  const int len  = (V - start < seglen) ? (V - start) : seglen;

  __shared__ unsigned int hist[NBINS_A];
  __shared__ float red[BLK_A / 64];
  __shared__ float s_m;
  __shared__ int   s_bstar;

  if (len <= 0) {
    if (tid == 0) { segmax[row * NSPLIT + seg] = -INFINITY;
                    segz  [row * NSPLIT + seg] = 0.f; }
    return;
  }

  for (int i = tid; i < NBINS_A; i += BLK_A) hist[i] = 0u;

  const float* __restrict__ base = logits + (size_t)row * V + start;
  const bool vec4 = ((len & 3) == 0) && ((((size_t)base) & 15) == 0);
  const int len4 = vec4 ? (len >> 2) : 0;
  const float4* b4 = reinterpret_cast<const float4*>(base);

  // ---- pass 1: segment max ----
  float m = -INFINITY;
  for (int i = tid; i < len4; i += BLK_A) {
    float4 v = b4[i];
    m = fmaxf(fmaxf(m, fmaxf(v.x, v.y)), fmaxf(v.z, v.w));
  }
  for (int i = (len4 << 2) + tid; i < len; i += BLK_A) m = fmaxf(m, base[i]);
  #pragma unroll
  for (int off = 32; off >= 1; off >>= 1) m = fmaxf(m, __shfl_xor(m, off, 64));
  if (lane == 0) red[wave] = m;
  __syncthreads();
  if (tid == 0) {
    float v = red[0];
    for (int w = 1; w < BLK_A / 64; ++w) v = fmaxf(v, red[w]);
    s_m = v;
  }
  __syncthreads();

  const float ms = s_m;
  const float lo = ms - SPAN;
  const float binscale = (float)NBINS_A / SPAN;
  const float invT = 1.0f / TEMP;

  // ---- pass 2: softmax partial (rel. ms) + histogram ----
  float zs = 0.f;
  for (int i = tid; i < len4; i += BLK_A) {
    float4 v = b4[i];
    #pragma unroll
    for (int c = 0; c < 4; ++c) {
      float l = (c == 0) ? v.x : (c == 1) ? v.y : (c == 2) ? v.z : v.w;
      zs += expf((l - ms) * invT);
      if (l > lo) {
        int b = (int)((l - lo) * binscale);
        if (b > NBINS_A - 1) b = NBINS_A - 1;
        atomicAdd(&hist[b], 1u);
      }
    }
  }
  for (int i = (len4 << 2) + tid; i < len; i += BLK_A) {
    float l = base[i];
    zs += expf((l - ms) * invT);
    if (l > lo) {
      int b = (int)((l - lo) * binscale);
      if (b > NBINS_A - 1) b = NBINS_A - 1;
      atomicAdd(&hist[b], 1u);
    }
  }
  #pragma unroll
  for (int off = 32; off >= 1; off >>= 1) zs += __shfl_xor(zs, off, 64);
  __syncthreads();              // hist complete; red[] reusable
  if (lane == 0) red[wave] = zs;
  __syncthreads();
  if (tid == 0) {
    float v = red[0];
    for (int w = 1; w < BLK_A / 64; ++w) v += red[w];
    segz  [row * NSPLIT + seg] = v;
    segmax[row * NSPLIT + seg] = ms;
  }

  // ---- threshold bin: largest b with suffix-count >= TOPK (wave 0) ----
  if (tid < 64) {
    unsigned int csum = 0;
    const int cbase = tid * BPL;
    for (int j = 0; j < BPL; ++j) csum += hist[cbase + j];
    unsigned int suf = 0;
    for (int l2 = 0; l2 < 64; ++l2) {
      unsigned int c2 = __shfl(csum, l2, 64);
      suf += (l2 >= tid) ? c2 : 0u;
    }
    unsigned long long bal = __ballot(suf >= (unsigned)TOPK);
    if (bal == 0ull) {
      if (tid == 0) s_bstar = 0;      // fewer than TOPK in window: take all
    } else {
      int L = 63 - __builtin_clzll(bal);
      if (tid == L) {
        unsigned int running = suf - csum;   // suffix above this chunk
        int bsel = cbase;
        for (int b = cbase + BPL - 1; b >= cbase; --b) {
          running += hist[b];
          if (running >= (unsigned)TOPK) { bsel = b; break; }
        }
        s_bstar = bsel;
      }
    }
  }
  __syncthreads();

  // ---- pass 3: collect candidates (bin >= bstar) into per-row buffer ----
  const int bstar = s_bstar;
  for (int i = tid; i < len4; i += BLK_A) {
    float4 v = b4[i];
    #pragma unroll
    for (int c = 0; c < 4; ++c) {
      float l = (c == 0) ? v.x : (c == 1) ? v.y : (c == 2) ? v.z : v.w;
      if (l > lo) {
        int b = (int)((l - lo) * binscale);
        if (b > NBINS_A - 1) b = NBINS_A - 1;
        if (b >= bstar) {
          unsigned int p = atomicAdd(&cnt[row], 1u);
          if (p < CAPR) {
            cand_v[(size_t)row * CAPR + p] = l;
            cand_i[(size_t)row * CAPR + p] = start + (i << 2) + c;
          }
        }
      }
    }
  }
  for (int i = (len4 << 2) + tid; i < len; i += BLK_A) {
    float l = base[i];
    if (l > lo) {
      int b = (int)((l - lo) * binscale);
      if (b > NBINS_A - 1) b = NBINS_A - 1;
      if (b >= bstar) {
        unsigned int p = atomicAdd(&cnt[row], 1u);
        if (p < CAPR) {
          cand_v[(size_t)row * CAPR + p] = l;
          cand_i[(size_t)row * CAPR + p] = start + i;
        }
      }
    }
  }
}

__global__ __launch_bounds__(64)
void finish_kernel(const float* __restrict__ segmax, const float* __restrict__ segz,
                   const float* __restrict__ cand_v, const int* __restrict__ cand_i,
                   const unsigned int* __restrict__ cnt,
                   const float* __restrict__ uvec, int* __restrict__ out)
{
  const int row  = blockIdx.x;
  const int lane = threadIdx.x;
  const float invT = 1.0f / TEMP;

  // global max + rescaled Z
  float sm = (lane < NSPLIT) ? segmax[row * NSPLIT + lane] : -INFINITY;
  float m = sm;
  #pragma unroll
  for (int off = 32; off >= 1; off >>= 1) m = fmaxf(m, __shfl_xor(m, off, 64));
  const float M = m;
  float zt = 0.f;
  if (lane < NSPLIT) zt = segz[row * NSPLIT + lane] * expf((sm - M) * invT);
  #pragma unroll
  for (int off = 32; off >= 1; off >>= 1) zt += __shfl_xor(zt, off, 64);
  const float Z = zt;

  int n = (int)cnt[row]; if (n > CAPR) n = CAPR;

  __shared__ float cv[CAPR];
  __shared__ int   ci[CAPR];
  __shared__ float kept_e[TOPK];
  __shared__ int   kept_i[TOPK];
  for (int i = lane; i < n; i += 64) {
    cv[i] = cand_v[(size_t)row * CAPR + i];
    ci[i] = cand_i[(size_t)row * CAPR + i];
  }
  __syncthreads();

  // selection: top min(m,50) in descending value order, nucleus cut at 0.9*Z
  const float Mx = M / TEMP;          // exact reference path: fl(M/0.7)
  const float thresh = 0.9f * Z;
  float cum = 0.f;
  int nk = 0;
  for (int k = 0; k < TOPK; ++k) {
    if (cum >= thresh) break;
    float bv = -INFINITY; int bi = 0x7fffffff; int bp = -1;
    for (int j = lane; j < n; j += 64) {
      float v = cv[j];
      if (v == -INFINITY) continue;
      int idx = ci[j];
      if (v > bv || (v == bv && idx < bi)) { bv = v; bi = idx; bp = j; }
    }
    #pragma unroll
    for (int off = 32; off >= 1; off >>= 1) {
      float ov = __shfl_xor(bv, off, 64);
      int   oi = __shfl_xor(bi, off, 64);
      int   op = __shfl_xor(bp, off, 64);
      if (op >= 0 && (bp < 0 || ov > bv || (ov == bv && oi < bi))) { bv = ov; bi = oi; bp = op; }
    }
    if (bp < 0) break;
    float x = cv[bp] / TEMP;          // exact per-element reference path
    float e = expf(x - Mx);
    if (lane == 0) { kept_e[nk] = e; kept_i[nk] = bi; }
    nk++;
    cum += e;
    cv[bp] = -INFINITY;               // all lanes write same value
  }
  __syncthreads();

  // rank-sort kept tokens by original index (all distinct)
  int   myi = 0x7fffffff;
  float mye = 0.f;
  if (lane < nk) { myi = kept_i[lane]; mye = kept_e[lane]; }
  int rank = 0;
  for (int j = 0; j < nk; ++j) rank += (kept_i[j] < myi) ? 1 : 0;
  __syncthreads();
  if (lane < nk) { cv[rank] = mye; ci[rank] = myi; }
  __syncthreads();

  if (lane == 0) {
    float S = 0.f;
    for (int j = 0; j < nk; ++j) S += cv[j];
    const float uu = uvec[row];
    float c = 0.f;
    int token = 0;                    // argmax over all-False -> 0
    for (int j = 0; j < nk; ++j) {
      float q = cv[j] / S;            // mirrors softmax per-element divide
      c += q;
      if (c >= uu) { token = ci[j]; break; }
    }
    out[row] = token;
  }
}

extern "C" void kernel_launch(void* const* d_in, const int* in_sizes, int n_in,
                              void* d_out, int out_size, void* d_ws, size_t ws_size,
                              hipStream_t stream) {
  const float* logits = (const float*)d_in[0];
  // d_in[1] = input_ids (unused: repetition_penalty == 1.0)
  const float* u = (const float*)d_in[2];
  int* out = (int*)d_out;
  const int B = in_sizes[2];
  const int V = in_sizes[0] / B;
  int seglen = (V + NSPLIT - 1) / NSPLIT;
  seglen = (seglen + 3) & ~3;

  // workspace layout (all 4-byte aligned):
  char* ws = (char*)d_ws;
  unsigned int* cnt = (unsigned int*)ws;                        // B
  float* segmax = (float*)(ws + ((size_t)B * 4 + 255 & ~255));  // B*NSPLIT
  float* segz   = segmax + (size_t)B * NSPLIT;                  // B*NSPLIT
  float* cand_v = segz   + (size_t)B * NSPLIT;                  // B*CAPR
  int*   cand_i = (int*)(cand_v + (size_t)B * CAPR);            // B*CAPR

  zero_cnt_kernel<<<dim3((B + 127) / 128), dim3(128), 0, stream>>>(cnt, B);
  seg_kernel<<<dim3(NSPLIT, B), dim3(BLK_A), 0, stream>>>(
      logits, segmax, segz, cand_v, cand_i, cnt, V, seglen);
  finish_kernel<<<dim3(B), dim3(64), 0, stream>>>(
      segmax, segz, cand_v, cand_i, cnt, u, out);
}

// Round 3
// 178.770 us; speedup vs baseline: 2.2790x; 2.2790x over previous
//
#include <hip/hip_runtime.h>
#include <cmath>

// Sampler: temperature(0.7) -> top-p(0.9, HF semantics) -> top-k(50)
// -> softmax -> inverse-CDF multinomial with given uniform u.
//
// R3: same structure as R2 (16 segments/row, 3 passes, finish kernel), but
// candidate extraction batches through LDS: one global atomicAdd per BLOCK
// (range reservation) instead of one per candidate. R2's per-candidate
// device-scope same-address atomics (return value used -> per-lane
// serialized cross-XCD line ping-pong) were the 267us stall.

constexpr int   NSPLIT  = 16;
constexpr int   BLK_A   = 256;
constexpr int   NBINS_A = 1024;
constexpr int   BPL     = NBINS_A / 64;   // bins per lane in wave-0 scan
constexpr int   TOPK    = 50;
constexpr float TEMP    = 0.7f;
constexpr float SPAN    = 8.4f;           // candidate window below segment max
constexpr int   CAPR    = 2048;           // per-row candidate capacity
constexpr int   CAPB    = 256;            // per-block candidate capacity (LDS)

__global__ void zero_cnt_kernel(unsigned int* cnt, int B) {
  int i = blockIdx.x * blockDim.x + threadIdx.x;
  if (i < B) cnt[i] = 0u;
}

__global__ __launch_bounds__(BLK_A)
void seg_kernel(const float* __restrict__ logits,
                float* __restrict__ segmax, float* __restrict__ segz,
                float* __restrict__ cand_v, int* __restrict__ cand_i,
                unsigned int* __restrict__ cnt,
                int V, int seglen)
{
  const int seg  = blockIdx.x;
  const int row  = blockIdx.y;
  const int tid  = threadIdx.x, lane = tid & 63, wave = tid >> 6;
  const int start = seg * seglen;
  const int len  = (V - start < seglen) ? (V - start) : seglen;

  __shared__ unsigned int hist[NBINS_A];
  __shared__ float red[BLK_A / 64];
  __shared__ float s_m;
  __shared__ int   s_bstar;
  __shared__ unsigned int s_np;      // block-local candidate count
  __shared__ unsigned int s_base;    // reserved base in per-row buffer
  __shared__ float bl_v[CAPB];
  __shared__ int   bl_i[CAPB];

  if (len <= 0) {
    if (tid == 0) { segmax[row * NSPLIT + seg] = -INFINITY;
                    segz  [row * NSPLIT + seg] = 0.f; }
    return;
  }

  for (int i = tid; i < NBINS_A; i += BLK_A) hist[i] = 0u;
  if (tid == 0) s_np = 0u;

  const float* __restrict__ base = logits + (size_t)row * V + start;
  const bool vec4 = ((len & 3) == 0) && ((((size_t)base) & 15) == 0);
  const int len4 = vec4 ? (len >> 2) : 0;
  const float4* b4 = reinterpret_cast<const float4*>(base);

  // ---- pass 1: segment max ----
  float m = -INFINITY;
  for (int i = tid; i < len4; i += BLK_A) {
    float4 v = b4[i];
    m = fmaxf(fmaxf(m, fmaxf(v.x, v.y)), fmaxf(v.z, v.w));
  }
  for (int i = (len4 << 2) + tid; i < len; i += BLK_A) m = fmaxf(m, base[i]);
  #pragma unroll
  for (int off = 32; off >= 1; off >>= 1) m = fmaxf(m, __shfl_xor(m, off, 64));
  if (lane == 0) red[wave] = m;
  __syncthreads();
  if (tid == 0) {
    float v = red[0];
    for (int w = 1; w < BLK_A / 64; ++w) v = fmaxf(v, red[w]);
    s_m = v;
  }
  __syncthreads();

  const float ms = s_m;
  const float lo = ms - SPAN;
  const float binscale = (float)NBINS_A / SPAN;
  const float invT = 1.0f / TEMP;

  // ---- pass 2: softmax partial (rel. ms) + histogram ----
  float zs = 0.f;
  for (int i = tid; i < len4; i += BLK_A) {
    float4 v = b4[i];
    #pragma unroll
    for (int c = 0; c < 4; ++c) {
      float l = (c == 0) ? v.x : (c == 1) ? v.y : (c == 2) ? v.z : v.w;
      zs += expf((l - ms) * invT);
      if (l > lo) {
        int b = (int)((l - lo) * binscale);
        if (b > NBINS_A - 1) b = NBINS_A - 1;
        atomicAdd(&hist[b], 1u);
      }
    }
  }
  for (int i = (len4 << 2) + tid; i < len; i += BLK_A) {
    float l = base[i];
    zs += expf((l - ms) * invT);
    if (l > lo) {
      int b = (int)((l - lo) * binscale);
      if (b > NBINS_A - 1) b = NBINS_A - 1;
      atomicAdd(&hist[b], 1u);
    }
  }
  #pragma unroll
  for (int off = 32; off >= 1; off >>= 1) zs += __shfl_xor(zs, off, 64);
  __syncthreads();              // hist complete; red[] reusable
  if (lane == 0) red[wave] = zs;
  __syncthreads();
  if (tid == 0) {
    float v = red[0];
    for (int w = 1; w < BLK_A / 64; ++w) v += red[w];
    segz  [row * NSPLIT + seg] = v;
    segmax[row * NSPLIT + seg] = ms;
  }

  // ---- threshold bin: largest b with suffix-count >= TOPK (wave 0) ----
  if (tid < 64) {
    unsigned int csum = 0;
    const int cbase = tid * BPL;
    for (int j = 0; j < BPL; ++j) csum += hist[cbase + j];
    unsigned int suf = 0;
    for (int l2 = 0; l2 < 64; ++l2) {
      unsigned int c2 = __shfl(csum, l2, 64);
      suf += (l2 >= tid) ? c2 : 0u;
    }
    unsigned long long bal = __ballot(suf >= (unsigned)TOPK);
    if (bal == 0ull) {
      if (tid == 0) s_bstar = 0;      // fewer than TOPK in window: take all
    } else {
      int L = 63 - __builtin_clzll(bal);
      if (tid == L) {
        unsigned int running = suf - csum;   // suffix above this chunk
        int bsel = cbase;
        for (int b = cbase + BPL - 1; b >= cbase; --b) {
          running += hist[b];
          if (running >= (unsigned)TOPK) { bsel = b; break; }
        }
        s_bstar = bsel;
      }
    }
  }
  __syncthreads();

  // ---- pass 3: collect candidates (bin >= bstar) into LDS, then one
  //      global reservation per block ----
  const int bstar = s_bstar;
  for (int i = tid; i < len4; i += BLK_A) {
    float4 v = b4[i];
    #pragma unroll
    for (int c = 0; c < 4; ++c) {
      float l = (c == 0) ? v.x : (c == 1) ? v.y : (c == 2) ? v.z : v.w;
      if (l > lo) {
        int b = (int)((l - lo) * binscale);
        if (b > NBINS_A - 1) b = NBINS_A - 1;
        if (b >= bstar) {
          unsigned int p = atomicAdd(&s_np, 1u);
          if (p < CAPB) { bl_v[p] = l; bl_i[p] = start + (i << 2) + c; }
          else {                                   // rare overflow: direct
            unsigned int g = atomicAdd(&cnt[row], 1u);
            if (g < CAPR) {
              cand_v[(size_t)row * CAPR + g] = l;
              cand_i[(size_t)row * CAPR + g] = start + (i << 2) + c;
            }
          }
        }
      }
    }
  }
  for (int i = (len4 << 2) + tid; i < len; i += BLK_A) {
    float l = base[i];
    if (l > lo) {
      int b = (int)((l - lo) * binscale);
      if (b > NBINS_A - 1) b = NBINS_A - 1;
      if (b >= bstar) {
        unsigned int p = atomicAdd(&s_np, 1u);
        if (p < CAPB) { bl_v[p] = l; bl_i[p] = start + i; }
        else {
          unsigned int g = atomicAdd(&cnt[row], 1u);
          if (g < CAPR) {
            cand_v[(size_t)row * CAPR + g] = l;
            cand_i[(size_t)row * CAPR + g] = start + i;
          }
        }
      }
    }
  }
  __syncthreads();
  unsigned int np = s_np; if (np > CAPB) np = CAPB;
  if (tid == 0) s_base = atomicAdd(&cnt[row], np);
  __syncthreads();
  const unsigned int gb = s_base;
  for (unsigned int i = tid; i < np; i += BLK_A) {
    unsigned int g = gb + i;
    if (g < CAPR) {
      cand_v[(size_t)row * CAPR + g] = bl_v[i];
      cand_i[(size_t)row * CAPR + g] = bl_i[i];
    }
  }
}

__global__ __launch_bounds__(64)
void finish_kernel(const float* __restrict__ segmax, const float* __restrict__ segz,
                   const float* __restrict__ cand_v, const int* __restrict__ cand_i,
                   const unsigned int* __restrict__ cnt,
                   const float* __restrict__ uvec, int* __restrict__ out)
{
  const int row  = blockIdx.x;
  const int lane = threadIdx.x;
  const float invT = 1.0f / TEMP;

  // global max + rescaled Z
  float sm = (lane < NSPLIT) ? segmax[row * NSPLIT + lane] : -INFINITY;
  float m = sm;
  #pragma unroll
  for (int off = 32; off >= 1; off >>= 1) m = fmaxf(m, __shfl_xor(m, off, 64));
  const float M = m;
  float zt = 0.f;
  if (lane < NSPLIT) zt = segz[row * NSPLIT + lane] * expf((sm - M) * invT);
  #pragma unroll
  for (int off = 32; off >= 1; off >>= 1) zt += __shfl_xor(zt, off, 64);
  const float Z = zt;

  int n = (int)cnt[row]; if (n > CAPR) n = CAPR;

  __shared__ float cv[CAPR];
  __shared__ int   ci[CAPR];
  __shared__ float kept_e[TOPK];
  __shared__ int   kept_i[TOPK];
  for (int i = lane; i < n; i += 64) {
    cv[i] = cand_v[(size_t)row * CAPR + i];
    ci[i] = cand_i[(size_t)row * CAPR + i];
  }
  __syncthreads();

  // selection: top min(m,50) in descending value order, nucleus cut at 0.9*Z
  const float Mx = M / TEMP;          // exact reference path: fl(M/0.7)
  const float thresh = 0.9f * Z;
  float cum = 0.f;
  int nk = 0;
  for (int k = 0; k < TOPK; ++k) {
    if (cum >= thresh) break;
    float bv = -INFINITY; int bi = 0x7fffffff; int bp = -1;
    for (int j = lane; j < n; j += 64) {
      float v = cv[j];
      if (v == -INFINITY) continue;
      int idx = ci[j];
      if (v > bv || (v == bv && idx < bi)) { bv = v; bi = idx; bp = j; }
    }
    #pragma unroll
    for (int off = 32; off >= 1; off >>= 1) {
      float ov = __shfl_xor(bv, off, 64);
      int   oi = __shfl_xor(bi, off, 64);
      int   op = __shfl_xor(bp, off, 64);
      if (op >= 0 && (bp < 0 || ov > bv || (ov == bv && oi < bi))) { bv = ov; bi = oi; bp = op; }
    }
    if (bp < 0) break;
    float x = cv[bp] / TEMP;          // exact per-element reference path
    float e = expf(x - Mx);
    if (lane == 0) { kept_e[nk] = e; kept_i[nk] = bi; }
    nk++;
    cum += e;
    cv[bp] = -INFINITY;               // all lanes write same value
  }
  __syncthreads();

  // rank-sort kept tokens by original index (all distinct)
  int   myi = 0x7fffffff;
  float mye = 0.f;
  if (lane < nk) { myi = kept_i[lane]; mye = kept_e[lane]; }
  int rank = 0;
  for (int j = 0; j < nk; ++j) rank += (kept_i[j] < myi) ? 1 : 0;
  __syncthreads();
  if (lane < nk) { cv[rank] = mye; ci[rank] = myi; }
  __syncthreads();

  if (lane == 0) {
    float S = 0.f;
    for (int j = 0; j < nk; ++j) S += cv[j];
    const float uu = uvec[row];
    float c = 0.f;
    int token = 0;                    // argmax over all-False -> 0
    for (int j = 0; j < nk; ++j) {
      float q = cv[j] / S;            // mirrors softmax per-element divide
      c += q;
      if (c >= uu) { token = ci[j]; break; }
    }
    out[row] = token;
  }
}

extern "C" void kernel_launch(void* const* d_in, const int* in_sizes, int n_in,
                              void* d_out, int out_size, void* d_ws, size_t ws_size,
                              hipStream_t stream) {
  const float* logits = (const float*)d_in[0];
  // d_in[1] = input_ids (unused: repetition_penalty == 1.0)
  const float* u = (const float*)d_in[2];
  int* out = (int*)d_out;
  const int B = in_sizes[2];
  const int V = in_sizes[0] / B;
  int seglen = (V + NSPLIT - 1) / NSPLIT;
  seglen = (seglen + 3) & ~3;

  // workspace layout (all 4-byte aligned):
  char* ws = (char*)d_ws;
  unsigned int* cnt = (unsigned int*)ws;                        // B
  float* segmax = (float*)(ws + (((size_t)B * 4 + 255) & ~(size_t)255)); // B*NSPLIT
  float* segz   = segmax + (size_t)B * NSPLIT;                  // B*NSPLIT
  float* cand_v = segz   + (size_t)B * NSPLIT;                  // B*CAPR
  int*   cand_i = (int*)(cand_v + (size_t)B * CAPR);            // B*CAPR

  zero_cnt_kernel<<<dim3((B + 127) / 128), dim3(128), 0, stream>>>(cnt, B);
  seg_kernel<<<dim3(NSPLIT, B), dim3(BLK_A), 0, stream>>>(
      logits, segmax, segz, cand_v, cand_i, cnt, V, seglen);
  finish_kernel<<<dim3(B), dim3(64), 0, stream>>>(
      segmax, segz, cand_v, cand_i, cnt, u, out);
}

// Round 4
// 109.290 us; speedup vs baseline: 3.7279x; 1.6357x over previous
//
#include <hip/hip_runtime.h>
#include <cmath>

// Sampler: temperature(0.7) -> top-p(0.9, HF semantics) -> top-k(50)
// -> softmax -> inverse-CDF multinomial with given uniform u.
//
// R4: finish_kernel was 138us (serial 50x argmax over ~880 LDS candidates,
// latency-bound). Replaced with one bitonic sort (2048 slots, 512 thr) whose
// comparator (value desc, index asc) reproduces the argmax order exactly;
// nucleus cut keeps the same sequential fp32 accumulation. seg_kernel
// unchanged from R3 (LDS-batched candidate reservation).

constexpr int   NSPLIT  = 16;
constexpr int   BLK_A   = 256;
constexpr int   NBINS_A = 1024;
constexpr int   BPL     = NBINS_A / 64;   // bins per lane in wave-0 scan
constexpr int   TOPK    = 50;
constexpr float TEMP    = 0.7f;
constexpr float SPAN    = 8.4f;           // candidate window below segment max
constexpr int   CAPR    = 2048;           // per-row candidate capacity
constexpr int   CAPB    = 256;            // per-block candidate capacity (LDS)
constexpr int   BLK_F   = 512;            // finish block size
constexpr int   NSORT   = 2048;           // sort width (== CAPR)

__global__ void zero_cnt_kernel(unsigned int* cnt, int B) {
  int i = blockIdx.x * blockDim.x + threadIdx.x;
  if (i < B) cnt[i] = 0u;
}

__global__ __launch_bounds__(BLK_A)
void seg_kernel(const float* __restrict__ logits,
                float* __restrict__ segmax, float* __restrict__ segz,
                float* __restrict__ cand_v, int* __restrict__ cand_i,
                unsigned int* __restrict__ cnt,
                int V, int seglen)
{
  const int seg  = blockIdx.x;
  const int row  = blockIdx.y;
  const int tid  = threadIdx.x, lane = tid & 63, wave = tid >> 6;
  const int start = seg * seglen;
  const int len  = (V - start < seglen) ? (V - start) : seglen;

  __shared__ unsigned int hist[NBINS_A];
  __shared__ float red[BLK_A / 64];
  __shared__ float s_m;
  __shared__ int   s_bstar;
  __shared__ unsigned int s_np;      // block-local candidate count
  __shared__ unsigned int s_base;    // reserved base in per-row buffer
  __shared__ float bl_v[CAPB];
  __shared__ int   bl_i[CAPB];

  if (len <= 0) {
    if (tid == 0) { segmax[row * NSPLIT + seg] = -INFINITY;
                    segz  [row * NSPLIT + seg] = 0.f; }
    return;
  }

  for (int i = tid; i < NBINS_A; i += BLK_A) hist[i] = 0u;
  if (tid == 0) s_np = 0u;

  const float* __restrict__ base = logits + (size_t)row * V + start;
  const bool vec4 = ((len & 3) == 0) && ((((size_t)base) & 15) == 0);
  const int len4 = vec4 ? (len >> 2) : 0;
  const float4* b4 = reinterpret_cast<const float4*>(base);

  // ---- pass 1: segment max ----
  float m = -INFINITY;
  for (int i = tid; i < len4; i += BLK_A) {
    float4 v = b4[i];
    m = fmaxf(fmaxf(m, fmaxf(v.x, v.y)), fmaxf(v.z, v.w));
  }
  for (int i = (len4 << 2) + tid; i < len; i += BLK_A) m = fmaxf(m, base[i]);
  #pragma unroll
  for (int off = 32; off >= 1; off >>= 1) m = fmaxf(m, __shfl_xor(m, off, 64));
  if (lane == 0) red[wave] = m;
  __syncthreads();
  if (tid == 0) {
    float v = red[0];
    for (int w = 1; w < BLK_A / 64; ++w) v = fmaxf(v, red[w]);
    s_m = v;
  }
  __syncthreads();

  const float ms = s_m;
  const float lo = ms - SPAN;
  const float binscale = (float)NBINS_A / SPAN;
  const float invT = 1.0f / TEMP;

  // ---- pass 2: softmax partial (rel. ms) + histogram ----
  float zs = 0.f;
  for (int i = tid; i < len4; i += BLK_A) {
    float4 v = b4[i];
    #pragma unroll
    for (int c = 0; c < 4; ++c) {
      float l = (c == 0) ? v.x : (c == 1) ? v.y : (c == 2) ? v.z : v.w;
      zs += expf((l - ms) * invT);
      if (l > lo) {
        int b = (int)((l - lo) * binscale);
        if (b > NBINS_A - 1) b = NBINS_A - 1;
        atomicAdd(&hist[b], 1u);
      }
    }
  }
  for (int i = (len4 << 2) + tid; i < len; i += BLK_A) {
    float l = base[i];
    zs += expf((l - ms) * invT);
    if (l > lo) {
      int b = (int)((l - lo) * binscale);
      if (b > NBINS_A - 1) b = NBINS_A - 1;
      atomicAdd(&hist[b], 1u);
    }
  }
  #pragma unroll
  for (int off = 32; off >= 1; off >>= 1) zs += __shfl_xor(zs, off, 64);
  __syncthreads();              // hist complete; red[] reusable
  if (lane == 0) red[wave] = zs;
  __syncthreads();
  if (tid == 0) {
    float v = red[0];
    for (int w = 1; w < BLK_A / 64; ++w) v += red[w];
    segz  [row * NSPLIT + seg] = v;
    segmax[row * NSPLIT + seg] = ms;
  }

  // ---- threshold bin: largest b with suffix-count >= TOPK (wave 0) ----
  if (tid < 64) {
    unsigned int csum = 0;
    const int cbase = tid * BPL;
    for (int j = 0; j < BPL; ++j) csum += hist[cbase + j];
    unsigned int suf = 0;
    for (int l2 = 0; l2 < 64; ++l2) {
      unsigned int c2 = __shfl(csum, l2, 64);
      suf += (l2 >= tid) ? c2 : 0u;
    }
    unsigned long long bal = __ballot(suf >= (unsigned)TOPK);
    if (bal == 0ull) {
      if (tid == 0) s_bstar = 0;      // fewer than TOPK in window: take all
    } else {
      int L = 63 - __builtin_clzll(bal);
      if (tid == L) {
        unsigned int running = suf - csum;   // suffix above this chunk
        int bsel = cbase;
        for (int b = cbase + BPL - 1; b >= cbase; --b) {
          running += hist[b];
          if (running >= (unsigned)TOPK) { bsel = b; break; }
        }
        s_bstar = bsel;
      }
    }
  }
  __syncthreads();

  // ---- pass 3: collect candidates (bin >= bstar) into LDS, then one
  //      global reservation per block ----
  const int bstar = s_bstar;
  for (int i = tid; i < len4; i += BLK_A) {
    float4 v = b4[i];
    #pragma unroll
    for (int c = 0; c < 4; ++c) {
      float l = (c == 0) ? v.x : (c == 1) ? v.y : (c == 2) ? v.z : v.w;
      if (l > lo) {
        int b = (int)((l - lo) * binscale);
        if (b > NBINS_A - 1) b = NBINS_A - 1;
        if (b >= bstar) {
          unsigned int p = atomicAdd(&s_np, 1u);
          if (p < CAPB) { bl_v[p] = l; bl_i[p] = start + (i << 2) + c; }
          else {                                   // rare overflow: direct
            unsigned int g = atomicAdd(&cnt[row], 1u);
            if (g < CAPR) {
              cand_v[(size_t)row * CAPR + g] = l;
              cand_i[(size_t)row * CAPR + g] = start + (i << 2) + c;
            }
          }
        }
      }
    }
  }
  for (int i = (len4 << 2) + tid; i < len; i += BLK_A) {
    float l = base[i];
    if (l > lo) {
      int b = (int)((l - lo) * binscale);
      if (b > NBINS_A - 1) b = NBINS_A - 1;
      if (b >= bstar) {
        unsigned int p = atomicAdd(&s_np, 1u);
        if (p < CAPB) { bl_v[p] = l; bl_i[p] = start + i; }
        else {
          unsigned int g = atomicAdd(&cnt[row], 1u);
          if (g < CAPR) {
            cand_v[(size_t)row * CAPR + g] = l;
            cand_i[(size_t)row * CAPR + g] = start + i;
          }
        }
      }
    }
  }
  __syncthreads();
  unsigned int np = s_np; if (np > CAPB) np = CAPB;
  if (tid == 0) s_base = atomicAdd(&cnt[row], np);
  __syncthreads();
  const unsigned int gb = s_base;
  for (unsigned int i = tid; i < np; i += BLK_A) {
    unsigned int g = gb + i;
    if (g < CAPR) {
      cand_v[(size_t)row * CAPR + g] = bl_v[i];
      cand_i[(size_t)row * CAPR + g] = bl_i[i];
    }
  }
}

__device__ __forceinline__ bool precedes(float va, int ia, float vb, int ib) {
  // "a comes before b": descending by value, ascending index on ties.
  return (va > vb) || (va == vb && ia < ib);
}

__global__ __launch_bounds__(BLK_F)
void finish_kernel(const float* __restrict__ segmax, const float* __restrict__ segz,
                   const float* __restrict__ cand_v, const int* __restrict__ cand_i,
                   const unsigned int* __restrict__ cnt,
                   const float* __restrict__ uvec, int* __restrict__ out)
{
  const int row  = blockIdx.x;
  const int tid  = threadIdx.x;
  const int lane = tid & 63;
  const float invT = 1.0f / TEMP;

  __shared__ float cv[NSORT];
  __shared__ int   ci[NSORT];
  __shared__ float ord_e[TOPK];
  __shared__ int   ord_i[TOPK];
  __shared__ int   s_nk;

  // global max + rescaled Z (every wave computes its own identical copy)
  float sm = (lane < NSPLIT) ? segmax[row * NSPLIT + lane] : -INFINITY;
  float m = sm;
  #pragma unroll
  for (int off = 32; off >= 1; off >>= 1) m = fmaxf(m, __shfl_xor(m, off, 64));
  const float M = m;
  float zt = (lane < NSPLIT) ? segz[row * NSPLIT + lane] * expf((sm - M) * invT) : 0.f;
  #pragma unroll
  for (int off = 32; off >= 1; off >>= 1) zt += __shfl_xor(zt, off, 64);
  const float Z = zt;

  int n = (int)cnt[row]; if (n > CAPR) n = CAPR;

  // load candidates, pad to NSORT
  for (int i = tid; i < NSORT; i += BLK_F) {
    if (i < n) {
      cv[i] = cand_v[(size_t)row * CAPR + i];
      ci[i] = cand_i[(size_t)row * CAPR + i];
    } else {
      cv[i] = -INFINITY;
      ci[i] = 0x7fffffff;
    }
  }
  __syncthreads();

  // bitonic sort: descending by value, index asc on ties
  for (int k2 = 2; k2 <= NSORT; k2 <<= 1) {
    for (int j = k2 >> 1; j > 0; j >>= 1) {
      for (int i = tid; i < NSORT; i += BLK_F) {
        int ixj = i ^ j;
        if (ixj > i) {
          float va = cv[i],  vb = cv[ixj];
          int   ia = ci[i],  ib = ci[ixj];
          bool up = ((i & k2) == 0);
          bool sw = up ? precedes(vb, ib, va, ia) : precedes(va, ia, vb, ib);
          if (sw) { cv[i] = vb; ci[i] = ib; cv[ixj] = va; ci[ixj] = ia; }
        }
      }
      __syncthreads();
    }
  }

  // ---- nucleus cut + rank-by-index (wave 0) ----
  if (tid < 64) {
    const float Mx = M / TEMP;          // exact reference path: fl(M/0.7)
    const float thresh = 0.9f * Z;
    float myv = cv[tid];                // sorted descending
    int   myi = ci[tid];
    int   valid = (tid < n) && (myv != -INFINITY);
    float e = 0.f;
    if (valid) { float x = myv / TEMP; e = expf(x - Mx); }  // exact path

    // sequential fp32 accumulation, replicated uniformly across lanes
    float cum = 0.f; int nk = 0;
    for (int k = 0; k < TOPK; ++k) {
      float ek = __shfl(e, k, 64);
      int   vk = __shfl(valid, k, 64);
      if (!vk) break;
      if (cum >= thresh) break;
      cum += ek; nk++;
    }

    // rank kept tokens by original index (all distinct)
    int rank = 0;
    for (int j = 0; j < nk; ++j) {
      int oj = __shfl(myi, j, 64);
      if (oj < myi) rank++;
    }
    if (tid < nk) { ord_e[rank] = e; ord_i[rank] = myi; }
    if (tid == 0) s_nk = nk;
  }
  __syncthreads();

  if (tid == 0) {
    const int nk = s_nk;
    float S = 0.f;
    for (int j = 0; j < nk; ++j) S += ord_e[j];
    const float uu = uvec[row];
    float c = 0.f;
    int token = 0;                      // argmax over all-False -> 0
    for (int j = 0; j < nk; ++j) {
      float q = ord_e[j] / S;           // mirrors softmax per-element divide
      c += q;
      if (c >= uu) { token = ord_i[j]; break; }
    }
    out[row] = token;
  }
}

extern "C" void kernel_launch(void* const* d_in, const int* in_sizes, int n_in,
                              void* d_out, int out_size, void* d_ws, size_t ws_size,
                              hipStream_t stream) {
  const float* logits = (const float*)d_in[0];
  // d_in[1] = input_ids (unused: repetition_penalty == 1.0)
  const float* u = (const float*)d_in[2];
  int* out = (int*)d_out;
  const int B = in_sizes[2];
  const int V = in_sizes[0] / B;
  int seglen = (V + NSPLIT - 1) / NSPLIT;
  seglen = (seglen + 3) & ~3;

  // workspace layout (all 4-byte aligned):
  char* ws = (char*)d_ws;
  unsigned int* cnt = (unsigned int*)ws;                        // B
  float* segmax = (float*)(ws + (((size_t)B * 4 + 255) & ~(size_t)255)); // B*NSPLIT
  float* segz   = segmax + (size_t)B * NSPLIT;                  // B*NSPLIT
  float* cand_v = segz   + (size_t)B * NSPLIT;                  // B*CAPR
  int*   cand_i = (int*)(cand_v + (size_t)B * CAPR);            // B*CAPR

  zero_cnt_kernel<<<dim3((B + 127) / 128), dim3(128), 0, stream>>>(cnt, B);
  seg_kernel<<<dim3(NSPLIT, B), dim3(BLK_A), 0, stream>>>(
      logits, segmax, segz, cand_v, cand_i, cnt, V, seglen);
  finish_kernel<<<dim3(B), dim3(BLK_F), 0, stream>>>(
      segmax, segz, cand_v, cand_i, cnt, u, out);
}

// Round 5
// 89.795 us; speedup vs baseline: 4.5372x; 1.2171x over previous
//
#include <hip/hip_runtime.h>
#include <cmath>

// Sampler: temperature(0.7) -> top-p(0.9, HF semantics) -> top-k(50)
// -> softmax -> inverse-CDF multinomial with given uniform u.
//
// R5: R4's 2048-wide bitonic sort in finish was still latency-bound (68us:
// 66 barrier-separated LDS stages at 2 waves/SIMD + cold-I$ unrolled code).
// Replace with: 1024-bin histogram over candidates -> global top-50
// threshold (same scan as seg) -> compact ~51 survivors -> R3-validated
// iterative wave-argmax in REGISTERS (2 cand/lane, shuffle butterfly).
// seg_kernel unchanged from R3/R4.

constexpr int   NSPLIT  = 16;
constexpr int   BLK_A   = 256;
constexpr int   NBINS_A = 1024;
constexpr int   BPL     = NBINS_A / 64;   // bins per lane in wave-0 scan
constexpr int   TOPK    = 50;
constexpr float TEMP    = 0.7f;
constexpr float SPAN    = 8.4f;           // candidate window below (seg/global) max
constexpr int   CAPR    = 2048;           // per-row candidate capacity
constexpr int   CAPB    = 256;            // per-block candidate capacity (LDS)
constexpr int   BLK_F   = 256;            // finish block size
constexpr int   NBINS_F = 1024;           // finish histogram bins
constexpr int   BPLF    = NBINS_F / 64;
constexpr int   CAPC    = 128;            // compacted-candidate capacity

__global__ void zero_cnt_kernel(unsigned int* cnt, int B) {
  int i = blockIdx.x * blockDim.x + threadIdx.x;
  if (i < B) cnt[i] = 0u;
}

__global__ __launch_bounds__(BLK_A)
void seg_kernel(const float* __restrict__ logits,
                float* __restrict__ segmax, float* __restrict__ segz,
                float* __restrict__ cand_v, int* __restrict__ cand_i,
                unsigned int* __restrict__ cnt,
                int V, int seglen)
{
  const int seg  = blockIdx.x;
  const int row  = blockIdx.y;
  const int tid  = threadIdx.x, lane = tid & 63, wave = tid >> 6;
  const int start = seg * seglen;
  const int len  = (V - start < seglen) ? (V - start) : seglen;

  __shared__ unsigned int hist[NBINS_A];
  __shared__ float red[BLK_A / 64];
  __shared__ float s_m;
  __shared__ int   s_bstar;
  __shared__ unsigned int s_np;      // block-local candidate count
  __shared__ unsigned int s_base;    // reserved base in per-row buffer
  __shared__ float bl_v[CAPB];
  __shared__ int   bl_i[CAPB];

  if (len <= 0) {
    if (tid == 0) { segmax[row * NSPLIT + seg] = -INFINITY;
                    segz  [row * NSPLIT + seg] = 0.f; }
    return;
  }

  for (int i = tid; i < NBINS_A; i += BLK_A) hist[i] = 0u;
  if (tid == 0) s_np = 0u;

  const float* __restrict__ base = logits + (size_t)row * V + start;
  const bool vec4 = ((len & 3) == 0) && ((((size_t)base) & 15) == 0);
  const int len4 = vec4 ? (len >> 2) : 0;
  const float4* b4 = reinterpret_cast<const float4*>(base);

  // ---- pass 1: segment max ----
  float m = -INFINITY;
  for (int i = tid; i < len4; i += BLK_A) {
    float4 v = b4[i];
    m = fmaxf(fmaxf(m, fmaxf(v.x, v.y)), fmaxf(v.z, v.w));
  }
  for (int i = (len4 << 2) + tid; i < len; i += BLK_A) m = fmaxf(m, base[i]);
  #pragma unroll
  for (int off = 32; off >= 1; off >>= 1) m = fmaxf(m, __shfl_xor(m, off, 64));
  if (lane == 0) red[wave] = m;
  __syncthreads();
  if (tid == 0) {
    float v = red[0];
    for (int w = 1; w < BLK_A / 64; ++w) v = fmaxf(v, red[w]);
    s_m = v;
  }
  __syncthreads();

  const float ms = s_m;
  const float lo = ms - SPAN;
  const float binscale = (float)NBINS_A / SPAN;
  const float invT = 1.0f / TEMP;

  // ---- pass 2: softmax partial (rel. ms) + histogram ----
  float zs = 0.f;
  for (int i = tid; i < len4; i += BLK_A) {
    float4 v = b4[i];
    #pragma unroll
    for (int c = 0; c < 4; ++c) {
      float l = (c == 0) ? v.x : (c == 1) ? v.y : (c == 2) ? v.z : v.w;
      zs += expf((l - ms) * invT);
      if (l > lo) {
        int b = (int)((l - lo) * binscale);
        if (b > NBINS_A - 1) b = NBINS_A - 1;
        atomicAdd(&hist[b], 1u);
      }
    }
  }
  for (int i = (len4 << 2) + tid; i < len; i += BLK_A) {
    float l = base[i];
    zs += expf((l - ms) * invT);
    if (l > lo) {
      int b = (int)((l - lo) * binscale);
      if (b > NBINS_A - 1) b = NBINS_A - 1;
      atomicAdd(&hist[b], 1u);
    }
  }
  #pragma unroll
  for (int off = 32; off >= 1; off >>= 1) zs += __shfl_xor(zs, off, 64);
  __syncthreads();              // hist complete; red[] reusable
  if (lane == 0) red[wave] = zs;
  __syncthreads();
  if (tid == 0) {
    float v = red[0];
    for (int w = 1; w < BLK_A / 64; ++w) v += red[w];
    segz  [row * NSPLIT + seg] = v;
    segmax[row * NSPLIT + seg] = ms;
  }

  // ---- threshold bin: largest b with suffix-count >= TOPK (wave 0) ----
  if (tid < 64) {
    unsigned int csum = 0;
    const int cbase = tid * BPL;
    for (int j = 0; j < BPL; ++j) csum += hist[cbase + j];
    unsigned int suf = 0;
    for (int l2 = 0; l2 < 64; ++l2) {
      unsigned int c2 = __shfl(csum, l2, 64);
      suf += (l2 >= tid) ? c2 : 0u;
    }
    unsigned long long bal = __ballot(suf >= (unsigned)TOPK);
    if (bal == 0ull) {
      if (tid == 0) s_bstar = 0;      // fewer than TOPK in window: take all
    } else {
      int L = 63 - __builtin_clzll(bal);
      if (tid == L) {
        unsigned int running = suf - csum;   // suffix above this chunk
        int bsel = cbase;
        for (int b = cbase + BPL - 1; b >= cbase; --b) {
          running += hist[b];
          if (running >= (unsigned)TOPK) { bsel = b; break; }
        }
        s_bstar = bsel;
      }
    }
  }
  __syncthreads();

  // ---- pass 3: collect candidates (bin >= bstar) into LDS, then one
  //      global reservation per block ----
  const int bstar = s_bstar;
  for (int i = tid; i < len4; i += BLK_A) {
    float4 v = b4[i];
    #pragma unroll
    for (int c = 0; c < 4; ++c) {
      float l = (c == 0) ? v.x : (c == 1) ? v.y : (c == 2) ? v.z : v.w;
      if (l > lo) {
        int b = (int)((l - lo) * binscale);
        if (b > NBINS_A - 1) b = NBINS_A - 1;
        if (b >= bstar) {
          unsigned int p = atomicAdd(&s_np, 1u);
          if (p < CAPB) { bl_v[p] = l; bl_i[p] = start + (i << 2) + c; }
          else {                                   // rare overflow: direct
            unsigned int g = atomicAdd(&cnt[row], 1u);
            if (g < CAPR) {
              cand_v[(size_t)row * CAPR + g] = l;
              cand_i[(size_t)row * CAPR + g] = start + (i << 2) + c;
            }
          }
        }
      }
    }
  }
  for (int i = (len4 << 2) + tid; i < len; i += BLK_A) {
    float l = base[i];
    if (l > lo) {
      int b = (int)((l - lo) * binscale);
      if (b > NBINS_A - 1) b = NBINS_A - 1;
      if (b >= bstar) {
        unsigned int p = atomicAdd(&s_np, 1u);
        if (p < CAPB) { bl_v[p] = l; bl_i[p] = start + i; }
        else {
          unsigned int g = atomicAdd(&cnt[row], 1u);
          if (g < CAPR) {
            cand_v[(size_t)row * CAPR + g] = l;
            cand_i[(size_t)row * CAPR + g] = start + i;
          }
        }
      }
    }
  }
  __syncthreads();
  unsigned int np = s_np; if (np > CAPB) np = CAPB;
  if (tid == 0) s_base = atomicAdd(&cnt[row], np);
  __syncthreads();
  const unsigned int gb = s_base;
  for (unsigned int i = tid; i < np; i += BLK_A) {
    unsigned int g = gb + i;
    if (g < CAPR) {
      cand_v[(size_t)row * CAPR + g] = bl_v[i];
      cand_i[(size_t)row * CAPR + g] = bl_i[i];
    }
  }
}

__global__ __launch_bounds__(BLK_F)
void finish_kernel(const float* __restrict__ segmax, const float* __restrict__ segz,
                   const float* __restrict__ cand_v, const int* __restrict__ cand_i,
                   const unsigned int* __restrict__ cnt,
                   const float* __restrict__ uvec, int* __restrict__ out)
{
  const int row  = blockIdx.x;
  const int tid  = threadIdx.x;
  const int lane = tid & 63;
  const float invT = 1.0f / TEMP;

  __shared__ unsigned int hist[NBINS_F];
  __shared__ float s_M, s_Z;
  __shared__ int   s_bstar;
  __shared__ unsigned int s_nc;
  __shared__ float fv[CAPC];
  __shared__ int   fi[CAPC];
  __shared__ float kept_e[TOPK];
  __shared__ int   kept_i[TOPK];
  __shared__ float ord_e[TOPK];
  __shared__ int   ord_i[TOPK];
  __shared__ int   s_nk;

  // wave 0: global max + rescaled Z
  if (tid < 64) {
    float sm = (lane < NSPLIT) ? segmax[row * NSPLIT + lane] : -INFINITY;
    float m = sm;
    #pragma unroll
    for (int off = 32; off >= 1; off >>= 1) m = fmaxf(m, __shfl_xor(m, off, 64));
    float zt = (lane < NSPLIT) ? segz[row * NSPLIT + lane] * expf((sm - m) * invT) : 0.f;
    #pragma unroll
    for (int off = 32; off >= 1; off >>= 1) zt += __shfl_xor(zt, off, 64);
    if (lane == 0) { s_M = m; s_Z = zt; s_nc = 0u; s_nk = 0; }
  }
  for (int i = tid; i < NBINS_F; i += BLK_F) hist[i] = 0u;
  __syncthreads();

  const float M  = s_M;
  const float lo = M - SPAN;
  const float binscale = (float)NBINS_F / SPAN;
  int n = (int)cnt[row]; if (n > CAPR) n = CAPR;

  // histogram of candidate values, anchored at global max
  const float* cvrow = cand_v + (size_t)row * CAPR;
  const int*   cirow = cand_i + (size_t)row * CAPR;
  for (int i = tid; i < n; i += BLK_F) {
    float v = cvrow[i];
    int b = (int)((v - lo) * binscale);
    if (b < 0) b = 0;
    if (b > NBINS_F - 1) b = NBINS_F - 1;
    atomicAdd(&hist[b], 1u);
  }
  __syncthreads();

  // wave 0: largest bin with suffix-count >= TOPK
  if (tid < 64) {
    unsigned int csum = 0;
    const int cbase = tid * BPLF;
    for (int j = 0; j < BPLF; ++j) csum += hist[cbase + j];
    unsigned int suf = 0;
    for (int l2 = 0; l2 < 64; ++l2) {
      unsigned int c2 = __shfl(csum, l2, 64);
      suf += (l2 >= tid) ? c2 : 0u;
    }
    unsigned long long bal = __ballot(suf >= (unsigned)TOPK);
    if (bal == 0ull) {
      if (tid == 0) s_bstar = 0;          // fewer than TOPK total: take all
    } else {
      int L = 63 - __builtin_clzll(bal);
      if (tid == L) {
        unsigned int running = suf - csum;
        int bsel = cbase;
        for (int b = cbase + BPLF - 1; b >= cbase; --b) {
          running += hist[b];
          if (running >= (unsigned)TOPK) { bsel = b; break; }
        }
        s_bstar = bsel;
      }
    }
  }
  __syncthreads();

  // compact survivors (bin >= bstar) into <=CAPC LDS slots
  const int bstar = s_bstar;
  for (int i = tid; i < n; i += BLK_F) {
    float v = cvrow[i];
    int b = (int)((v - lo) * binscale);
    if (b < 0) b = 0;
    if (b > NBINS_F - 1) b = NBINS_F - 1;
    if (b >= bstar) {
      unsigned int p = atomicAdd(&s_nc, 1u);
      if (p < CAPC) { fv[p] = v; fi[p] = cirow[i]; }
    }
  }
  __syncthreads();

  // ---- wave 0: iterative argmax selection in registers (R3 semantics) ----
  if (tid < 64) {
    int nc = (int)s_nc; if (nc > CAPC) nc = CAPC;
    float c0v = (lane < nc)      ? fv[lane]      : -INFINITY;
    int   c0i = (lane < nc)      ? fi[lane]      : 0x7fffffff;
    float c1v = (lane + 64 < nc) ? fv[lane + 64] : -INFINITY;
    int   c1i = (lane + 64 < nc) ? fi[lane + 64] : 0x7fffffff;

    const float Mx = M / TEMP;            // exact reference path: fl(M/0.7)
    const float thresh = 0.9f * s_Z;
    float cum = 0.f;
    int nk = 0;
    for (int k = 0; k < TOPK; ++k) {
      if (cum >= thresh) break;
      // per-lane best of two (value desc, index asc)
      float bv; int bi;
      if (c0v > c1v || (c0v == c1v && c0i < c1i)) { bv = c0v; bi = c0i; }
      else                                        { bv = c1v; bi = c1i; }
      // wave argmax butterfly
      #pragma unroll
      for (int off = 32; off >= 1; off >>= 1) {
        float ov = __shfl_xor(bv, off, 64);
        int   oi = __shfl_xor(bi, off, 64);
        if (ov > bv || (ov == bv && oi < bi)) { bv = ov; bi = oi; }
      }
      if (bv == -INFINITY) break;
      float x = bv / TEMP;                // exact per-element reference path
      float e = expf(x - Mx);
      if (lane == 0) { kept_e[nk] = e; kept_i[nk] = bi; }
      nk++;
      cum += e;
      if (c0i == bi) c0v = -INFINITY, c0i = 0x7fffffff;
      if (c1i == bi) c1v = -INFINITY, c1i = 0x7fffffff;
    }

    // rank kept tokens by original index (all distinct); kept_* just written
    // by lane 0 -- exchange through shuffles to avoid extra barriers
    float mye = 0.f; int myi = 0x7fffffff;
    if (lane == 0) {
      // lane 0 holds the arrays; push element k to lane k
    }
    // simple approach: lane k reads kept_* via shuffle from lane 0's LDS writes
    // (LDS writes by lane 0 are visible within the same wave after s_waitcnt,
    // which the compiler inserts before the reads below)
    if (lane < nk) { mye = kept_e[lane]; myi = kept_i[lane]; }
    int rank = 0;
    for (int j = 0; j < nk; ++j) {
      int oj = __shfl(myi, j, 64);
      int vj = (j < nk) ? 1 : 0;
      if (vj && oj < myi) rank++;
    }
    if (lane < nk) { ord_e[rank] = mye; ord_i[rank] = myi; }
    if (lane == 0) s_nk = nk;
  }
  __syncthreads();

  if (tid == 0) {
    const int nk = s_nk;
    float S = 0.f;
    for (int j = 0; j < nk; ++j) S += ord_e[j];
    const float uu = uvec[row];
    float c = 0.f;
    int token = 0;                        // argmax over all-False -> 0
    for (int j = 0; j < nk; ++j) {
      float q = ord_e[j] / S;             // mirrors softmax per-element divide
      c += q;
      if (c >= uu) { token = ord_i[j]; break; }
    }
    out[row] = token;
  }
}

extern "C" void kernel_launch(void* const* d_in, const int* in_sizes, int n_in,
                              void* d_out, int out_size, void* d_ws, size_t ws_size,
                              hipStream_t stream) {
  const float* logits = (const float*)d_in[0];
  // d_in[1] = input_ids (unused: repetition_penalty == 1.0)
  const float* u = (const float*)d_in[2];
  int* out = (int*)d_out;
  const int B = in_sizes[2];
  const int V = in_sizes[0] / B;
  int seglen = (V + NSPLIT - 1) / NSPLIT;
  seglen = (seglen + 3) & ~3;

  // workspace layout (all 4-byte aligned):
  char* ws = (char*)d_ws;
  unsigned int* cnt = (unsigned int*)ws;                        // B
  float* segmax = (float*)(ws + (((size_t)B * 4 + 255) & ~(size_t)255)); // B*NSPLIT
  float* segz   = segmax + (size_t)B * NSPLIT;                  // B*NSPLIT
  float* cand_v = segz   + (size_t)B * NSPLIT;                  // B*CAPR
  int*   cand_i = (int*)(cand_v + (size_t)B * CAPR);            // B*CAPR

  zero_cnt_kernel<<<dim3((B + 127) / 128), dim3(128), 0, stream>>>(cnt, B);
  seg_kernel<<<dim3(NSPLIT, B), dim3(BLK_A), 0, stream>>>(
      logits, segmax, segz, cand_v, cand_i, cnt, V, seglen);
  finish_kernel<<<dim3(B), dim3(BLK_F), 0, stream>>>(
      segmax, segz, cand_v, cand_i, cnt, u, out);
}

// Round 6
// 58.161 us; speedup vs baseline: 7.0051x; 1.5439x over previous
//
#include <hip/hip_runtime.h>
#include <cmath>

// Sampler: temperature(0.7) -> top-p(0.9, HF semantics) -> top-k(50)
// -> softmax -> inverse-CDF multinomial with given uniform u.
//
// R6: finish was 48us of serial-shuffle latency (50x6 dependent ds_bpermute
// argmax + 64-shuffle scans). Replaced by: LDS-chunk suffix scan (independent
// broadcast reads), all-pairs ranking (same comparator as argmax), per-rank
// exp, lane-0 sequential fp32 nucleus/CDF over prefetchable LDS reads.
// seg: fixed per-(row,seg) candidate slots + cnt16 (no global atomics, no
// zero kernel); same LDS-chunk scan.

constexpr int   NSPLIT = 16;
constexpr int   BLK_A  = 256;
constexpr int   NBINS  = 1024;
constexpr int   BPL    = NBINS / 64;     // bins per lane in scan
constexpr int   TOPK   = 50;
constexpr float TEMP   = 0.7f;
constexpr float SPAN   = 8.4f;           // candidate window below anchor max
constexpr int   CAPSEG = 128;            // fixed slots per (row,seg)
constexpr int   NCAND  = NSPLIT * CAPSEG;
constexpr int   BLK_F  = 256;
constexpr int   CAPC   = 128;            // compacted survivors cap

__global__ __launch_bounds__(BLK_A)
void seg_kernel(const float* __restrict__ logits,
                float* __restrict__ segmax, float* __restrict__ segz,
                float* __restrict__ cand_v, int* __restrict__ cand_i,
                unsigned int* __restrict__ cnt16,
                int V, int seglen)
{
  const int seg  = blockIdx.x;
  const int row  = blockIdx.y;
  const int tid  = threadIdx.x, lane = tid & 63, wave = tid >> 6;
  const int start = seg * seglen;
  const int len  = (V - start < seglen) ? (V - start) : seglen;

  __shared__ unsigned int hist[NBINS];
  __shared__ unsigned int chunk[64];
  __shared__ float red[BLK_A / 64];
  __shared__ float s_m;
  __shared__ int   s_bstar;
  __shared__ unsigned int s_np;
  __shared__ float bl_v[CAPSEG];
  __shared__ int   bl_i[CAPSEG];

  if (len <= 0) {
    if (tid == 0) { segmax[row * NSPLIT + seg] = -INFINITY;
                    segz  [row * NSPLIT + seg] = 0.f;
                    cnt16 [row * NSPLIT + seg] = 0u; }
    return;
  }

  for (int i = tid; i < NBINS; i += BLK_A) hist[i] = 0u;
  if (tid == 0) s_np = 0u;

  const float* __restrict__ base = logits + (size_t)row * V + start;
  const bool vec4 = ((len & 3) == 0) && ((((size_t)base) & 15) == 0);
  const int len4 = vec4 ? (len >> 2) : 0;
  const float4* b4 = reinterpret_cast<const float4*>(base);

  // ---- pass 1: segment max ----
  float m = -INFINITY;
  for (int i = tid; i < len4; i += BLK_A) {
    float4 v = b4[i];
    m = fmaxf(fmaxf(m, fmaxf(v.x, v.y)), fmaxf(v.z, v.w));
  }
  for (int i = (len4 << 2) + tid; i < len; i += BLK_A) m = fmaxf(m, base[i]);
  #pragma unroll
  for (int off = 32; off >= 1; off >>= 1) m = fmaxf(m, __shfl_xor(m, off, 64));
  if (lane == 0) red[wave] = m;
  __syncthreads();
  if (tid == 0) {
    float v = red[0];
    for (int w = 1; w < BLK_A / 64; ++w) v = fmaxf(v, red[w]);
    s_m = v;
  }
  __syncthreads();

  const float ms = s_m;
  const float lo = ms - SPAN;
  const float binscale = (float)NBINS / SPAN;
  const float invT = 1.0f / TEMP;

  // ---- pass 2: softmax partial (rel. ms) + histogram ----
  float zs = 0.f;
  for (int i = tid; i < len4; i += BLK_A) {
    float4 v = b4[i];
    #pragma unroll
    for (int c = 0; c < 4; ++c) {
      float l = (c == 0) ? v.x : (c == 1) ? v.y : (c == 2) ? v.z : v.w;
      zs += expf((l - ms) * invT);
      if (l > lo) {
        int b = (int)((l - lo) * binscale);
        if (b > NBINS - 1) b = NBINS - 1;
        atomicAdd(&hist[b], 1u);
      }
    }
  }
  for (int i = (len4 << 2) + tid; i < len; i += BLK_A) {
    float l = base[i];
    zs += expf((l - ms) * invT);
    if (l > lo) {
      int b = (int)((l - lo) * binscale);
      if (b > NBINS - 1) b = NBINS - 1;
      atomicAdd(&hist[b], 1u);
    }
  }
  #pragma unroll
  for (int off = 32; off >= 1; off >>= 1) zs += __shfl_xor(zs, off, 64);
  __syncthreads();              // hist complete
  if (lane == 0) red[wave] = zs;

  // per-lane chunk counts for the scan
  if (tid < 64) {
    unsigned int csum = 0;
    const int cb = tid * BPL;
    #pragma unroll
    for (int j = 0; j < BPL; ++j) csum += hist[cb + j];
    chunk[tid] = csum;
  }
  __syncthreads();
  if (tid == 0) {
    float v = red[0];
    for (int w = 1; w < BLK_A / 64; ++w) v += red[w];
    segz  [row * NSPLIT + seg] = v;
    segmax[row * NSPLIT + seg] = ms;
  }
  // ---- threshold: largest bin with suffix >= TOPK (wave 0, LDS broadcast) ----
  if (tid < 64) {
    unsigned int csum = chunk[tid];
    unsigned int suf = 0;
    for (int l2 = 0; l2 < 64; ++l2) {      // independent broadcast reads
      unsigned int c2 = chunk[l2];
      suf += (l2 >= tid) ? c2 : 0u;
    }
    unsigned long long bal = __ballot(suf >= (unsigned)TOPK);
    if (bal == 0ull) {
      if (tid == 0) s_bstar = 0;           // fewer than TOPK in window
    } else {
      int L = 63 - __builtin_clzll(bal);
      if (tid == L) {
        unsigned int running = suf - csum;
        const int cb = tid * BPL;
        unsigned int h[BPL];
        #pragma unroll
        for (int j = 0; j < BPL; ++j) h[j] = hist[cb + j];  // prefetch
        int bsel = cb;
        #pragma unroll
        for (int j = BPL - 1; j >= 0; --j) {
          running += h[j];
          if (running >= (unsigned)TOPK) { bsel = cb + j; break; }
        }
        s_bstar = bsel;
      }
    }
  }
  __syncthreads();

  // ---- pass 3: collect candidates (bin >= bstar) into LDS ----
  const int bstar = s_bstar;
  for (int i = tid; i < len4; i += BLK_A) {
    float4 v = b4[i];
    #pragma unroll
    for (int c = 0; c < 4; ++c) {
      float l = (c == 0) ? v.x : (c == 1) ? v.y : (c == 2) ? v.z : v.w;
      if (l > lo) {
        int b = (int)((l - lo) * binscale);
        if (b > NBINS - 1) b = NBINS - 1;
        if (b >= bstar) {
          unsigned int p = atomicAdd(&s_np, 1u);
          if (p < CAPSEG) { bl_v[p] = l; bl_i[p] = start + (i << 2) + c; }
        }
      }
    }
  }
  for (int i = (len4 << 2) + tid; i < len; i += BLK_A) {
    float l = base[i];
    if (l > lo) {
      int b = (int)((l - lo) * binscale);
      if (b > NBINS - 1) b = NBINS - 1;
      if (b >= bstar) {
        unsigned int p = atomicAdd(&s_np, 1u);
        if (p < CAPSEG) { bl_v[p] = l; bl_i[p] = start + i; }
      }
    }
  }
  __syncthreads();
  unsigned int np = s_np; if (np > CAPSEG) np = CAPSEG;
  float* cvout = cand_v + ((size_t)row * NSPLIT + seg) * CAPSEG;
  int*   ciout = cand_i + ((size_t)row * NSPLIT + seg) * CAPSEG;
  for (unsigned int i = tid; i < np; i += BLK_A) { cvout[i] = bl_v[i]; ciout[i] = bl_i[i]; }
  if (tid == 0) cnt16[row * NSPLIT + seg] = np;
}

__global__ __launch_bounds__(BLK_F)
void finish_kernel(const float* __restrict__ segmax, const float* __restrict__ segz,
                   const float* __restrict__ cand_v, const int* __restrict__ cand_i,
                   const unsigned int* __restrict__ cnt16,
                   const float* __restrict__ uvec, int* __restrict__ out)
{
  const int row  = blockIdx.x;
  const int tid  = threadIdx.x;
  const int lane = tid & 63;
  const float invT = 1.0f / TEMP;

  __shared__ unsigned int hist[NBINS];
  __shared__ unsigned int chunk[64];
  __shared__ unsigned int cnt_s[NSPLIT];
  __shared__ float s_M, s_Z;
  __shared__ int   s_bstar;
  __shared__ unsigned int s_nc;
  __shared__ float fv[CAPC];
  __shared__ int   fi[CAPC];
  __shared__ float ov_[CAPC];     // rank-ordered values
  __shared__ int   oi_[CAPC];     // rank-ordered indices
  __shared__ float eo[64];        // e per rank (ranks < TOPK <= 64)
  __shared__ float o2e[64];       // index-sorted kept e
  __shared__ int   o2i[64];
  __shared__ int   s_nk;

  if (tid < NSPLIT) cnt_s[tid] = cnt16[row * NSPLIT + tid];
  if (tid < 64) {
    float sm = (lane < NSPLIT) ? segmax[row * NSPLIT + lane] : -INFINITY;
    float m = sm;
    #pragma unroll
    for (int off = 32; off >= 1; off >>= 1) m = fmaxf(m, __shfl_xor(m, off, 64));
    float zt = (lane < NSPLIT) ? segz[row * NSPLIT + lane] * expf((sm - m) * invT) : 0.f;
    #pragma unroll
    for (int off = 32; off >= 1; off >>= 1) zt += __shfl_xor(zt, off, 64);
    if (lane == 0) { s_M = m; s_Z = zt; s_nc = 0u; }
  }
  for (int i = tid; i < NBINS; i += BLK_F) hist[i] = 0u;
  __syncthreads();

  const float M  = s_M;
  const float lo = M - SPAN;
  const float binscale = (float)NBINS / SPAN;
  const float* cvrow = cand_v + (size_t)row * NCAND;
  const int*   cirow = cand_i + (size_t)row * NCAND;

  // histogram of candidates, anchored at global max
  for (int i = tid; i < NCAND; i += BLK_F) {
    int sg = i >> 7;               // CAPSEG = 128
    int ix = i & (CAPSEG - 1);
    if ((unsigned)ix < cnt_s[sg]) {
      float v = cvrow[i];
      int b = (int)((v - lo) * binscale);
      b = (b < 0) ? 0 : ((b > NBINS - 1) ? (NBINS - 1) : b);
      atomicAdd(&hist[b], 1u);
    }
  }
  __syncthreads();

  if (tid < 64) {
    unsigned int csum = 0;
    const int cb = tid * BPL;
    #pragma unroll
    for (int j = 0; j < BPL; ++j) csum += hist[cb + j];
    chunk[tid] = csum;
  }
  __syncthreads();
  if (tid < 64) {
    unsigned int csum = chunk[tid];
    unsigned int suf = 0;
    for (int l2 = 0; l2 < 64; ++l2) {
      unsigned int c2 = chunk[l2];
      suf += (l2 >= tid) ? c2 : 0u;
    }
    unsigned long long bal = __ballot(suf >= (unsigned)TOPK);
    if (bal == 0ull) {
      if (tid == 0) s_bstar = 0;
    } else {
      int L = 63 - __builtin_clzll(bal);
      if (tid == L) {
        unsigned int running = suf - csum;
        const int cb = tid * BPL;
        unsigned int h[BPL];
        #pragma unroll
        for (int j = 0; j < BPL; ++j) h[j] = hist[cb + j];
        int bsel = cb;
        #pragma unroll
        for (int j = BPL - 1; j >= 0; --j) {
          running += h[j];
          if (running >= (unsigned)TOPK) { bsel = cb + j; break; }
        }
        s_bstar = bsel;
      }
    }
  }
  __syncthreads();

  // compact survivors (bin >= bstar)
  const int bstar = s_bstar;
  for (int i = tid; i < NCAND; i += BLK_F) {
    int sg = i >> 7;
    int ix = i & (CAPSEG - 1);
    if ((unsigned)ix < cnt_s[sg]) {
      float v = cvrow[i];
      int b = (int)((v - lo) * binscale);
      b = (b < 0) ? 0 : ((b > NBINS - 1) ? (NBINS - 1) : b);
      if (b >= bstar) {
        unsigned int p = atomicAdd(&s_nc, 1u);
        if (p < CAPC) { fv[p] = v; fi[p] = cirow[i]; }
      }
    }
  }
  __syncthreads();

  // ---- all-pairs descending rank (value desc, index asc) + scatter ----
  const int ns = ((int)s_nc < CAPC) ? (int)s_nc : CAPC;
  if (tid < 64) {
    float c0v = (lane < ns)      ? fv[lane]      : 0.f;
    int   c0i = (lane < ns)      ? fi[lane]      : 0;
    float c1v = (lane + 64 < ns) ? fv[lane + 64] : 0.f;
    int   c1i = (lane + 64 < ns) ? fi[lane + 64] : 0;
    int r0 = 0, r1 = 0;
    for (int j = 0; j < ns; ++j) {           // LDS broadcast reads, pipelined
      float vj = fv[j]; int ij = fi[j];
      if (vj > c0v || (vj == c0v && ij < c0i)) ++r0;
      if (vj > c1v || (vj == c1v && ij < c1i)) ++r1;
    }
    if (lane < ns)      { ov_[r0] = c0v; oi_[r0] = c0i; }
    if (lane + 64 < ns) { ov_[r1] = c1v; oi_[r1] = c1i; }
  }
  __syncthreads();

  // ---- per-rank exp on the exact reference path ----
  const float Mx = M / TEMP;                 // fl(M/0.7)
  if (tid < 64 && lane < ns && lane < TOPK) {
    float x = ov_[lane] / TEMP;              // fl(v/0.7) per element
    eo[lane] = expf(x - Mx);
  }
  __syncthreads();

  // ---- sequential fp32 nucleus scan (lane 0; reads pipeline, adds serial) ----
  if (tid == 0) {
    const float thresh = 0.9f * s_Z;
    const int nkmax = (ns < TOPK) ? ns : TOPK;
    float cum = 0.f; int nk = 0;
    for (int k = 0; k < TOPK; ++k) {
      float ek = eo[k];
      bool take = (k < nkmax) && (cum < thresh);
      if (take) { cum += ek; nk++; }
    }
    s_nk = nk;
  }
  __syncthreads();

  // ---- rank kept tokens by original index ----
  const int nk = s_nk;
  if (tid < 64 && lane < nk) {
    int myi = oi_[lane];
    int rank = 0;
    for (int j = 0; j < nk; ++j) rank += (oi_[j] < myi) ? 1 : 0;
    o2e[rank] = eo[lane]; o2i[rank] = myi;
  }
  __syncthreads();

  // ---- sequential CDF sample (lane 0) ----
  if (tid == 0) {
    float S = 0.f;
    for (int j = 0; j < nk; ++j) S += o2e[j];
    const float uu = uvec[row];
    float c = 0.f; int token = 0; int found = 0;
    for (int j = 0; j < nk; ++j) {
      float q = o2e[j] / S;                  // mirrors softmax per-element divide
      c += q;
      if (!found && c >= uu) { token = o2i[j]; found = 1; }
    }
    out[row] = token;
  }
}

extern "C" void kernel_launch(void* const* d_in, const int* in_sizes, int n_in,
                              void* d_out, int out_size, void* d_ws, size_t ws_size,
                              hipStream_t stream) {
  const float* logits = (const float*)d_in[0];
  // d_in[1] = input_ids (unused: repetition_penalty == 1.0)
  const float* u = (const float*)d_in[2];
  int* out = (int*)d_out;
  const int B = in_sizes[2];
  const int V = in_sizes[0] / B;
  int seglen = (V + NSPLIT - 1) / NSPLIT;
  seglen = (seglen + 3) & ~3;

  // workspace layout (4-byte aligned):
  char* ws = (char*)d_ws;
  float* segmax = (float*)ws;                                   // B*NSPLIT
  float* segz   = segmax + (size_t)B * NSPLIT;                  // B*NSPLIT
  unsigned int* cnt16 = (unsigned int*)(segz + (size_t)B * NSPLIT); // B*NSPLIT
  float* cand_v = (float*)(cnt16 + (size_t)B * NSPLIT);         // B*NCAND
  int*   cand_i = (int*)(cand_v + (size_t)B * NCAND);           // B*NCAND

  seg_kernel<<<dim3(NSPLIT, B), dim3(BLK_A), 0, stream>>>(
      logits, segmax, segz, cand_v, cand_i, cnt16, V, seglen);
  finish_kernel<<<dim3(B), dim3(BLK_F), 0, stream>>>(
      segmax, segz, cand_v, cand_i, cnt16, u, out);
}